// Round 17
// baseline (4733.401 us; speedup 1.0000x reference)
//
#include <hip/hip_runtime.h>
#include <hip/hip_bf16.h>
#include <cstdint>

// ---------------------------------------------------------------------------
// 2-layer LSTM, SEQ=512 B=64 IN=512 HID=1024.
// R17 = R16 (champion @3.83ms) with the consume side restructured:
//  - stage32w: wave-local gated staging. Wave wv stages the 8KB column-stripe
//    of source blocks 4wv..4wv+3, gated on THOSE 4 flags only (4-lane ballot
//    spin). 8 waves x 4 flags = all-32 coverage before the block syncthreads
//    (ring-reuse safety preserved), but each wave starts staging as soon as
//    its own sources publish -> staging overlaps the arrival spread.
//  - L1's producer dependency is point-to-point: its gate slice gring[.,
//    hid*4..] for hid in [32j,32j+32) is written only by producer block j
//    (byte ranges [256j,256j+256) both sides) -> spin on pf[j] alone.
//  - top-of-loop bulk polls + syncthreads deleted (stage self-gates; all
//    xp/LDS WAR hazards have >=1 syncthreads between read/write pairs).
// Data path, publishes, flags layout identical to R16: two half-batch
// pipelines x {L0, producer, L1} x 32 blocks; 32 hid x 32 bat per block;
// weights VGPR-pinned; line-padded per-block flags, plain sc0|sc1 stores.
// ---------------------------------------------------------------------------

typedef __attribute__((ext_vector_type(8))) short short8;    // 8 bf16
typedef __attribute__((ext_vector_type(4))) short short4b;   // 4 bf16
typedef __attribute__((ext_vector_type(4))) float f32x4;

#define AS1 __attribute__((address_space(1)))
#define AS3 __attribute__((address_space(3)))

static __device__ __forceinline__ void gload_lds16(const void* g, void* l) {
  __builtin_amdgcn_global_load_lds((const AS1 unsigned int*)g, (AS3 unsigned int*)l,
                                   16, 0, 0);
}

static __device__ __forceinline__ float sigmoidf_(float x) {
  return 1.f / (1.f + __expf(-x));
}

static __device__ __forceinline__ float bf2f(short s) {
  union { unsigned u; float f; } v;
  v.u = ((unsigned)(unsigned short)s) << 16;
  return v.f;
}

static __device__ __forceinline__ unsigned f2bfbits(float f) {
  __hip_bfloat16 h = __float2bfloat16(f);
  union { __hip_bfloat16 h; unsigned short u; } v;
  v.h = h;
  return (unsigned)v.u;
}

// LLC-coherent raw ops
static __device__ __forceinline__ f32x4 ld16_llc(const void* p) {
  f32x4 r;
  asm volatile("global_load_dwordx4 %0, %1, off sc0 sc1" : "=v"(r) : "v"(p) : "memory");
  return r;
}
static __device__ __forceinline__ uint2 ld8_llc(const void* p) {
  uint2 r;
  asm volatile("global_load_dwordx2 %0, %1, off sc0 sc1" : "=v"(r) : "v"(p) : "memory");
  return r;
}
static __device__ __forceinline__ void st16_llc(void* p, f32x4 v) {
  asm volatile("global_store_dwordx4 %0, %1, off sc0 sc1" :: "v"(p), "v"(v) : "memory");
}
static __device__ __forceinline__ void st4_llc(void* p, unsigned v) {
  asm volatile("global_store_dword %0, %1, off sc0 sc1" :: "v"(p), "v"(v) : "memory");
}

// wave-local gated stage of [32 bat][1024 hid] bf16 (64 KB) into swizzled LDS.
// Wave wv stages byte-cols [wv*256, wv*256+256) = source blocks 4wv..4wv+3;
// if f != null, first spins (4 lanes, ballot) on those blocks' padded flags.
// Lane map part16 = (c&15) ^ (row&7) keeps LDS writes conflict-free under the
// XOR swizzle (bijective within each row). Trailing vmcnt(0) drains ALL
// outstanding loads (incl. any issued by the caller before this).
static __device__ __forceinline__ void stage32w(const char* src, const unsigned* f,
                                                unsigned tgt, char* smem, int tid) {
  const int wv = tid >> 6;
  const int lane = tid & 63;
  if (f) {
    const unsigned* a = f + (wv * 4 + (lane & 3)) * 32;
    for (;;) {
      unsigned v = (lane < 4)
          ? __hip_atomic_load(a, __ATOMIC_RELAXED, __HIP_MEMORY_SCOPE_AGENT)
          : tgt;
      if (!__ballot(v < tgt)) break;
    }
  }
  f32x4 tmp[8];
#pragma unroll
  for (int it = 0; it < 8; ++it) {
    int c = it * 64 + lane;
    int row = c >> 4;
    int part = (c & 15) ^ (row & 7);
    tmp[it] = ld16_llc(src + row * 2048 + wv * 256 + part * 16);
  }
  asm volatile("s_waitcnt vmcnt(0)" ::: "memory");
#pragma unroll
  for (int it = 0; it < 8; ++it) {
    int c = it * 64 + lane;
    int row = c >> 4;
    int part = (c & 15) ^ (row & 7);
    int bo = row * 2048 + wv * 256 + part * 16;
    *(f32x4*)(smem + (bo ^ ((row & 7) << 4))) = tmp[it];
  }
}

// publish completion: data drained to LLC, then ONE plain flag store to this
// block's private (line-padded) flag slot.
static __device__ __forceinline__ void arrive_flag(unsigned* slot, unsigned val, int tid) {
  asm volatile("s_waitcnt vmcnt(0)" ::: "memory");  // this wave's stores at LLC
  __syncthreads();                                   // => all waves drained
  if (tid == 0) st4_llc(slot, val);
}

// one-wave poll over 32 line-padded flags (used only for the ring throttle).
static __device__ __forceinline__ void pollf(const unsigned* f, unsigned tgt, int lane) {
  const unsigned* a = f + (lane & 31) * 32;   // 32 words = 128B stride
  while (__hip_atomic_load(a, __ATOMIC_RELAXED, __HIP_MEMORY_SCOPE_AGENT) < tgt) {
  }
}

// --------------------------- f32 -> bf16 convert ---------------------------
__global__ void cvt_bf16(const float* __restrict__ in, __hip_bfloat16* __restrict__ out,
                         int n4) {
  int i = blockIdx.x * 256 + threadIdx.x;
  if (i >= n4) return;
  float4 v = ((const float4*)in)[i];
  out[i * 4 + 0] = __float2bfloat16(v.x);
  out[i * 4 + 1] = __float2bfloat16(v.y);
  out[i * 4 + 2] = __float2bfloat16(v.z);
  out[i * 4 + 3] = __float2bfloat16(v.w);
}

// --------------- f32 -> bf16 with gate-row permutation ---------------------
// out[(hid*4+g)*K + k] = in[(g*1024+hid)*K + k]   (only for the L0 GEMM B)
__global__ void cvt_permrow(const float* __restrict__ in, __hip_bfloat16* __restrict__ out,
                            int K) {
  int k4 = blockIdx.x * 256 + threadIdx.x;
  if (k4 >= (K >> 2)) return;
  int rp = blockIdx.y;
  int src = (rp & 3) * 1024 + (rp >> 2);
  float4 v = ((const float4*)(in + (size_t)src * K))[k4];
  __hip_bfloat16* o = out + (size_t)rp * K + k4 * 4;
  o[0] = __float2bfloat16(v.x);
  o[1] = __float2bfloat16(v.y);
  o[2] = __float2bfloat16(v.z);
  o[3] = __float2bfloat16(v.w);
}

// ------------------ bias sum with gate-row permutation ---------------------
__global__ void bias_perm(const float* __restrict__ b1, const float* __restrict__ b2,
                          float* __restrict__ o) {
  int i = blockIdx.x * 256 + threadIdx.x;  // i = hid*4+g
  if (i >= 4096) return;
  int src = (i & 3) * 1024 + (i >> 2);
  o[i] = b1[src] + b2[src];
}

// ------------------------------ state init --------------------------------
__global__ void init_state(const float* __restrict__ h0, const float* __restrict__ c0,
                           __hip_bfloat16* __restrict__ h_init, float* __restrict__ c_state,
                           int n) {
  int i = blockIdx.x * 256 + threadIdx.x;
  if (i >= n) return;
  h_init[i] = __float2bfloat16(h0[i]);
  c_state[i] = c0[i];
}

// ------------------------------- finalize ---------------------------------
__global__ void finalize_out(const float* __restrict__ hf, const float* __restrict__ cst,
                             float* __restrict__ out_h, float* __restrict__ out_c, int n) {
  int i = blockIdx.x * 256 + threadIdx.x;
  if (i >= n) return;
  out_h[i] = hf[i];
  out_c[i] = cst[i];
}

// --------------------- big GEMM: C = A @ B^T + bias ------------------------
__global__ __launch_bounds__(256) void gemm_bt_bias(
    const __hip_bfloat16* __restrict__ A, const __hip_bfloat16* __restrict__ B,
    __hip_bfloat16* __restrict__ C, const float* __restrict__ bias, int K, int N) {
  const int tid = threadIdx.x;
  const int lane = tid & 63;
  const int wv = tid >> 6;
  const int l15 = lane & 15, l4 = lane >> 4;
  const int bm = blockIdx.x * 128;
  const int bn = blockIdx.y * 128;
  __shared__ alignas(16) __hip_bfloat16 As[128 * 64];
  __shared__ alignas(16) __hip_bfloat16 Bs[128 * 64];
  f32x4 acc[4][4] = {};
  const int wm = (wv >> 1) * 64;
  const int wn = (wv & 1) * 64;

  for (int kt = 0; kt < K; kt += 64) {
    if (kt) __syncthreads();
#pragma unroll
    for (int it = 0; it < 4; ++it) {
      int ci = it * 256 + tid;
      int row = ci >> 3, c8 = ci & 7;
      gload_lds16(A + (bm + row) * K + kt + c8 * 8, As + (it * 256 + wv * 64) * 8);
      gload_lds16(B + (bn + row) * K + kt + c8 * 8, Bs + (it * 256 + wv * 64) * 8);
    }
    __syncthreads();
#pragma unroll
    for (int kk = 0; kk < 64; kk += 32) {
      short8 a[4], b[4];
#pragma unroll
      for (int m = 0; m < 4; ++m)
        a[m] = *(const short8*)(As + (wm + m * 16 + l15) * 64 + kk + l4 * 8);
#pragma unroll
      for (int n = 0; n < 4; ++n)
        b[n] = *(const short8*)(Bs + (wn + n * 16 + l15) * 64 + kk + l4 * 8);
#pragma unroll
      for (int m = 0; m < 4; ++m)
#pragma unroll
        for (int n = 0; n < 4; ++n)
          acc[m][n] = __builtin_amdgcn_mfma_f32_16x16x32_bf16(a[m], b[n], acc[m][n], 0, 0, 0);
    }
  }
#pragma unroll
  for (int n = 0; n < 4; ++n) {
    int col = bn + wn + n * 16 + l15;
    float bs = bias[col];
#pragma unroll
    for (int m = 0; m < 4; ++m) {
#pragma unroll
      for (int j = 0; j < 4; ++j) {
        int row = bm + wm + m * 16 + l4 * 4 + j;
        C[(size_t)row * N + col] = __float2bfloat16(acc[m][n][j] + bs);
      }
    }
  }
}

// ------------- two half-batch three-role persistent pipelines --------------
// LDS: [0,65536) stage; [65536,+8192) xp transpose buffer.
// Flags (per pipeline p, base = ctrs + p*3072 words):
//   l0f@+0, pf@+1024, l1f@+2048; each role = 32 slots x 32-word stride.
__global__ __launch_bounds__(512, 1) void lstm_pipeline(
    const __hip_bfloat16* __restrict__ Gin,    // [512][64][4096] L0 preact
    const __hip_bfloat16* __restrict__ Whh0,   // [4096][1024] raw
    const __hip_bfloat16* __restrict__ Whh1,   // [4096][1024] raw
    const __hip_bfloat16* __restrict__ Wih1,   // [4096][1024] raw
    const float* __restrict__ bias1,           // [4096] gate-permuted
    const __hip_bfloat16* __restrict__ hinit,  // [2][64][1024]
    __hip_bfloat16* __restrict__ y0b,          // [2][512][32][1024]
    __hip_bfloat16* __restrict__ gring,        // [2][8][32][4096]
    __hip_bfloat16* __restrict__ h1r,          // [2][2][32][1024]
    float* __restrict__ yout,                  // [512][64][1024] f32 (d_out)
    float* __restrict__ cst,                   // [2][64][1024]
    float* __restrict__ hf,                    // [2][64][1024]
    unsigned* __restrict__ ctrs) {
  extern __shared__ char smem[];
  const int tid = threadIdx.x;
  const int lane = tid & 63;
  const int wv = tid >> 6;                     // 0..7 = hidden row-strip
  const int l15 = lane & 15, l4 = lane >> 4;
  const int bid = blockIdx.x;
  const int pipe = bid >= 96;
  const int wid = pipe ? bid - 96 : bid;       // 0..95 within pipeline
  const int gbat = pipe * 32;                  // pipeline's batch base
  __hip_bfloat16* xp = (__hip_bfloat16*)(smem + 65536);
  unsigned* l0f = ctrs + pipe * 3072;
  unsigned* pf  = l0f + 1024;
  unsigned* l1f = l0f + 2048;
  __hip_bfloat16* y0p = y0b + (size_t)pipe * 512 * 32768;
  __hip_bfloat16* grp_ = gring + (size_t)pipe * 1048576;
  __hip_bfloat16* h1p = h1r + (size_t)pipe * 65536;

  if (wid < 32) {
    // ========================== L0 recurrence ==============================
    const int m = wid;
    const int bbase = m * 32;                  // 32 hidden units
    const int hid = bbase + wv * 4 + l4;
    const int grow = (l15 & 3) * 1024 + bbase + wv * 4 + (l15 >> 2);
    const __hip_bfloat16* wrow = Whh0 + (size_t)grow * 1024 + l4 * 8;
    short8 a[32];
#pragma unroll
    for (int kk = 0; kk < 32; ++kk) a[kk] = *(const short8*)(wrow + kk * 32);
#pragma unroll
    for (int kk = 0; kk < 32; ++kk) asm volatile("" : "+v"(a[kk]));

    float cS[2];
#pragma unroll
    for (int s = 0; s < 2; ++s)
      cS[s] = cst[(gbat + s * 16 + l15) * 1024 + hid];

    short4b gv0 = *(const short4b*)(Gin + (gbat + l15) * 4096 + hid * 4);
    short4b gv1 = *(const short4b*)(Gin + (gbat + 16 + l15) * 4096 + hid * 4);

    for (int t = 0; t < 512; ++t) {
      stage32w(t ? (const char*)(y0p + (size_t)(t - 1) * 32768)
                 : (const char*)(hinit + (size_t)gbat * 1024),
               t ? l0f : nullptr, (unsigned)t, smem, tid);
      __syncthreads();

      f32x4 acc[2][4] = {};
#pragma unroll
      for (int kk = 0; kk < 32; ++kk) {
        int ko = kk * 64 + l4 * 16;
#pragma unroll
        for (int s = 0; s < 2; ++s) {
          int bl = s * 16 + l15;               // local batch 0..31
          short8 b = *(const short8*)(smem + ((bl * 2048 + ko) ^ ((bl & 7) << 4)));
          acc[s][kk & 3] =
              __builtin_amdgcn_mfma_f32_16x16x32_bf16(a[kk], b, acc[s][kk & 3], 0, 0, 0);
        }
      }

#pragma unroll
      for (int s = 0; s < 2; ++s) {
        int bl = s * 16 + l15;
        int bat = gbat + bl;
        const short4b gv = s ? gv1 : gv0;
        float gi = acc[s][0][0] + acc[s][1][0] + acc[s][2][0] + acc[s][3][0] + bf2f(gv[0]);
        float gf = acc[s][0][1] + acc[s][1][1] + acc[s][2][1] + acc[s][3][1] + bf2f(gv[1]);
        float gg = acc[s][0][2] + acc[s][1][2] + acc[s][2][2] + acc[s][3][2] + bf2f(gv[2]);
        float go = acc[s][0][3] + acc[s][1][3] + acc[s][2][3] + acc[s][3][3] + bf2f(gv[3]);
        float i_ = sigmoidf_(gi);
        float f_ = sigmoidf_(gf);
        float g_ = tanhf(gg);
        float o_ = sigmoidf_(go);
        cS[s] = f_ * cS[s] + i_ * g_;
        float h = o_ * tanhf(cS[s]);
        xp[bl * 32 + wv * 4 + l4] = __float2bfloat16(h);
        if (t == 511) {
          hf[bat * 1024 + hid] = h;
          cst[bat * 1024 + hid] = cS[s];
        }
      }
      __syncthreads();
      if (tid < 128) {  // 32 bats x 32 hid bf16 = 2KB: 32 rows x 4 x 16B
        int b_ = tid >> 2, part = tid & 3;
        f32x4 v = *(const f32x4*)(xp + b_ * 32 + part * 8);
        st16_llc(y0p + (size_t)t * 32768 + b_ * 1024 + bbase + part * 8, v);
      }
      arrive_flag(l0f + m * 32, (unsigned)(t + 1), tid);
      if (t < 511) {  // Gin prefetch for t+1 (drained by next stage32w)
        gv0 = *(const short4b*)(Gin + (size_t)(t + 1) * 262144 + (gbat + l15) * 4096 + hid * 4);
        gv1 = *(const short4b*)(Gin + (size_t)(t + 1) * 262144 + (gbat + 16 + l15) * 4096 + hid * 4);
      }
    }

  } else if (wid < 64) {
    // ====================== Gin1 producer ==================================
    const int pp = wid - 32;
    const int bbase = pp * 32;
    const int hid = bbase + wv * 4 + l4;
    const int grow = (l15 & 3) * 1024 + bbase + wv * 4 + (l15 >> 2);
    const __hip_bfloat16* wrow = Wih1 + (size_t)grow * 1024 + l4 * 8;  // RAW layout
    short8 a[32];
#pragma unroll
    for (int kk = 0; kk < 32; ++kk) a[kk] = *(const short8*)(wrow + kk * 32);
#pragma unroll
    for (int kk = 0; kk < 32; ++kk) asm volatile("" : "+v"(a[kk]));

    const f32x4 bv = *(const f32x4*)(bias1 + hid * 4);

    for (int t = 0; t < 512; ++t) {
      // wave1: ring throttle vs L1 (8-slot gring, slack 5). Ordered before
      // any publish via the stage syncthreads.
      if (t >= 6 && tid >= 64 && tid < 128) pollf(l1f, (unsigned)(t - 5), lane);
      stage32w((const char*)(y0p + (size_t)t * 32768), l0f, (unsigned)(t + 1),
               smem, tid);
      __syncthreads();

      f32x4 acc[2][4] = {};
#pragma unroll
      for (int kk = 0; kk < 32; ++kk) {
        int ko = kk * 64 + l4 * 16;
#pragma unroll
        for (int s = 0; s < 2; ++s) {
          int bl = s * 16 + l15;
          short8 b = *(const short8*)(smem + ((bl * 2048 + ko) ^ ((bl & 7) << 4)));
          acc[s][kk & 3] =
              __builtin_amdgcn_mfma_f32_16x16x32_bf16(a[kk], b, acc[s][kk & 3], 0, 0, 0);
        }
      }

      // xp: [32 bat][128 gate-cols] bf16 (8 KB, 256B/row)
#pragma unroll
      for (int s = 0; s < 2; ++s) {
        int bl = s * 16 + l15;
        float g0 = acc[s][0][0] + acc[s][1][0] + acc[s][2][0] + acc[s][3][0] + bv[0];
        float g1 = acc[s][0][1] + acc[s][1][1] + acc[s][2][1] + acc[s][3][1] + bv[1];
        float g2 = acc[s][0][2] + acc[s][1][2] + acc[s][2][2] + acc[s][3][2] + bv[2];
        float g3 = acc[s][0][3] + acc[s][1][3] + acc[s][2][3] + acc[s][3][3] + bv[3];
        uint2 u;
        u.x = f2bfbits(g0) | (f2bfbits(g1) << 16);
        u.y = f2bfbits(g2) | (f2bfbits(g3) << 16);
        *(uint2*)(xp + bl * 128 + (wv * 4 + l4) * 4) = u;
      }
      __syncthreads();
      {
        // 32 rows x 16 x 16B = 256B/row, all 512 threads
        __hip_bfloat16* gdst = grp_ + (size_t)(t & 7) * 131072;
        int b_ = tid >> 4, part = tid & 15;
        f32x4 v = *(const f32x4*)(xp + b_ * 128 + part * 8);
        st16_llc(gdst + (size_t)b_ * 4096 + bbase * 4 + part * 8, v);
      }
      arrive_flag(pf + pp * 32, (unsigned)(t + 1), tid);
    }

  } else {
    // ========================== L1 recurrence ==============================
    const int j = wid - 64;
    const int bbase = j * 32;
    const int hid = bbase + wv * 4 + l4;
    const int grow = (l15 & 3) * 1024 + bbase + wv * 4 + (l15 >> 2);
    const __hip_bfloat16* wrow = Whh1 + (size_t)grow * 1024 + l4 * 8;
    short8 a[32];
#pragma unroll
    for (int kk = 0; kk < 32; ++kk) a[kk] = *(const short8*)(wrow + kk * 32);
#pragma unroll
    for (int kk = 0; kk < 32; ++kk) asm volatile("" : "+v"(a[kk]));

    float cS[2];
#pragma unroll
    for (int s = 0; s < 2; ++s)
      cS[s] = cst[65536 + (gbat + s * 16 + l15) * 1024 + hid];

    for (int t = 0; t < 512; ++t) {
      // point-to-point: this block's gate slice is written ONLY by producer j
      while (__hip_atomic_load(pf + j * 32, __ATOMIC_RELAXED,
                               __HIP_MEMORY_SCOPE_AGENT) < (unsigned)(t + 1)) {
      }
      const __hip_bfloat16* gsrc = grp_ + (size_t)(t & 7) * 131072;
      uint2 gu[2];
#pragma unroll
      for (int s = 0; s < 2; ++s)
        gu[s] = ld8_llc(gsrc + (size_t)(s * 16 + l15) * 4096 + hid * 4);
      // h1 stage (wave-local gated on l1f); vmcnt(0) inside drains gu too
      stage32w(t ? (const char*)(h1p + (size_t)((t - 1) & 1) * 32768)
                 : (const char*)(hinit + 65536 + (size_t)gbat * 1024),
               t ? l1f : nullptr, (unsigned)t, smem, tid);
      __syncthreads();

      f32x4 acc[2][4] = {};
#pragma unroll
      for (int kk = 0; kk < 32; ++kk) {
        int ko = kk * 64 + l4 * 16;
#pragma unroll
        for (int s = 0; s < 2; ++s) {
          int bl = s * 16 + l15;
          short8 b = *(const short8*)(smem + ((bl * 2048 + ko) ^ ((bl & 7) << 4)));
          acc[s][kk & 3] =
              __builtin_amdgcn_mfma_f32_16x16x32_bf16(a[kk], b, acc[s][kk & 3], 0, 0, 0);
        }
      }

#pragma unroll
      for (int s = 0; s < 2; ++s) {
        int bl = s * 16 + l15;
        int bat = gbat + bl;
        union { uint2 u; short ss[4]; } gp;
        gp.u = gu[s];
        float gi = acc[s][0][0] + acc[s][1][0] + acc[s][2][0] + acc[s][3][0] + bf2f(gp.ss[0]);
        float gf = acc[s][0][1] + acc[s][1][1] + acc[s][2][1] + acc[s][3][1] + bf2f(gp.ss[1]);
        float gg = acc[s][0][2] + acc[s][1][2] + acc[s][2][2] + acc[s][3][2] + bf2f(gp.ss[2]);
        float go = acc[s][0][3] + acc[s][1][3] + acc[s][2][3] + acc[s][3][3] + bf2f(gp.ss[3]);
        float i_ = sigmoidf_(gi);
        float f_ = sigmoidf_(gf);
        float g_ = tanhf(gg);
        float o_ = sigmoidf_(go);
        cS[s] = f_ * cS[s] + i_ * g_;
        float h = o_ * tanhf(cS[s]);
        xp[bl * 32 + wv * 4 + l4] = __float2bfloat16(h);
        if (t == 511) {
          hf[65536 + bat * 1024 + hid] = h;
          cst[65536 + bat * 1024 + hid] = cS[s];
        }
      }
      __syncthreads();
      if (tid < 128) {  // 32 bats x 32 hid bf16: 32 rows x 4 x 16B
        int b_ = tid >> 2, part = tid & 3;
        f32x4 v = *(const f32x4*)(xp + b_ * 32 + part * 8);
        st16_llc(h1p + (size_t)(t & 1) * 32768 + b_ * 1024 + bbase + part * 8, v);
      }
      arrive_flag(l1f + j * 32, (unsigned)(t + 1), tid);

      // yout f32 off the critical path: 32 bats x 32 hid f32 = 32 x 8 x 16B
      if (tid < 256) {
        int b_ = tid >> 3, part = tid & 7;
        short4b hv = *(const short4b*)(xp + b_ * 32 + part * 4);
        f32x4 v;
        v[0] = bf2f(hv[0]); v[1] = bf2f(hv[1]); v[2] = bf2f(hv[2]); v[3] = bf2f(hv[3]);
        *(f32x4*)(yout + (size_t)t * 65536 + (size_t)(gbat + b_) * 1024 + bbase + part * 4) = v;
      }
    }
  }
}

// ---------------------------------------------------------------------------
extern "C" void kernel_launch(void* const* d_in, const int* in_sizes, int n_in,
                              void* d_out_, int out_size, void* d_ws, size_t ws_size,
                              hipStream_t stream) {
  (void)in_sizes; (void)n_in; (void)out_size; (void)ws_size;
  const float* x      = (const float*)d_in[0];
  const float* h0     = (const float*)d_in[1];
  const float* c0     = (const float*)d_in[2];
  const float* w_ih_0 = (const float*)d_in[3];
  const float* w_hh_0 = (const float*)d_in[4];
  const float* b_ih_0 = (const float*)d_in[5];
  const float* b_hh_0 = (const float*)d_in[6];
  const float* w_ih_1 = (const float*)d_in[7];
  const float* w_hh_1 = (const float*)d_in[8];
  const float* b_ih_1 = (const float*)d_in[9];
  const float* b_hh_1 = (const float*)d_in[10];
  float* out = (float*)d_out_;

  char* p = (char*)d_ws;
  auto alloc = [&](size_t bytes) { char* r = p; p += (bytes + 255) & ~(size_t)255; return r; };
  __hip_bfloat16* xb    = (__hip_bfloat16*)alloc(33554432);
  __hip_bfloat16* wbih0 = (__hip_bfloat16*)alloc(4194304);    // permuted rows (GEMM B)
  __hip_bfloat16* wbhh0 = (__hip_bfloat16*)alloc(8388608);    // raw
  __hip_bfloat16* wbih1 = (__hip_bfloat16*)alloc(8388608);    // raw
  __hip_bfloat16* wbhh1 = (__hip_bfloat16*)alloc(8388608);    // raw
  __hip_bfloat16* y0b   = (__hip_bfloat16*)alloc(67108864);   // [2][512][32][1024]
  __hip_bfloat16* Gin   = (__hip_bfloat16*)alloc(268435456);  // L0 preact (full)
  __hip_bfloat16* gring = (__hip_bfloat16*)alloc(4194304);    // [2][8][32][4096]
  __hip_bfloat16* h1r   = (__hip_bfloat16*)alloc(262144);     // [2][2][32][1024]
  __hip_bfloat16* hinit = (__hip_bfloat16*)alloc(262144);     // [2][64][1024]
  float* bsum0          = (float*)alloc(16384);
  float* bsum1          = (float*)alloc(16384);
  float* cst            = (float*)alloc(524288);
  float* hf             = (float*)alloc(524288);
  unsigned* ctrs        = (unsigned*)alloc(32768);            // 2 x 3 x 32 x 128B

  (void)hipFuncSetAttribute((const void*)lstm_pipeline,
                            hipFuncAttributeMaxDynamicSharedMemorySize, 73728);

  cvt_bf16<<<16777216 / 4 / 256, 256, 0, stream>>>(x, xb, 16777216 / 4);
  cvt_permrow<<<dim3(1, 4096), 256, 0, stream>>>(w_ih_0, wbih0, 512);
  cvt_bf16<<<4194304 / 4 / 256, 256, 0, stream>>>(w_hh_0, wbhh0, 4194304 / 4);
  cvt_bf16<<<4194304 / 4 / 256, 256, 0, stream>>>(w_ih_1, wbih1, 4194304 / 4);  // RAW
  cvt_bf16<<<4194304 / 4 / 256, 256, 0, stream>>>(w_hh_1, wbhh1, 4194304 / 4);
  bias_perm<<<16, 256, 0, stream>>>(b_ih_0, b_hh_0, bsum0);
  bias_perm<<<16, 256, 0, stream>>>(b_ih_1, b_hh_1, bsum1);
  init_state<<<131072 / 256, 256, 0, stream>>>(h0, c0, hinit, cst, 131072);
  (void)hipMemsetAsync(ctrs, 0, 32768, stream);

  // L0 preactivations (full batch)
  gemm_bt_bias<<<dim3(256, 32), 256, 0, stream>>>(xb, wbih0, Gin, bsum0, 512, 4096);

  // two half-batch three-role pipelines (one cooperative launch)
  {
    const __hip_bfloat16* g_ = Gin;
    const __hip_bfloat16* w0_ = wbhh0;
    const __hip_bfloat16* w1_ = wbhh1;
    const __hip_bfloat16* wi_ = wbih1;
    const float* b1_ = bsum1;
    const __hip_bfloat16* hi_ = hinit;
    __hip_bfloat16* y0_ = y0b;
    __hip_bfloat16* gr_ = gring;
    __hip_bfloat16* h1_ = h1r;
    float* yo_ = out;
    float* c_ = cst;
    float* hf_ = hf;
    unsigned* ct_ = ctrs;
    void* args[] = {&g_, &w0_, &w1_, &wi_, &b1_, &hi_, &y0_, &gr_, &h1_,
                    &yo_, &c_, &hf_, &ct_};
    (void)hipLaunchCooperativeKernel((void*)lstm_pipeline, dim3(192), dim3(512),
                                     args, 73728, stream);
  }

  finalize_out<<<131072 / 256, 256, 0, stream>>>(hf, cst, out + 33554432, out + 33685504, 131072);
}

// Round 18
// 3816.954 us; speedup vs baseline: 1.2401x; 1.2401x over previous
//
#include <hip/hip_runtime.h>
#include <hip/hip_bf16.h>
#include <cstdint>

// ---------------------------------------------------------------------------
// 2-layer LSTM, SEQ=512 B=64 IN=512 HID=1024.
// R18 = R16 (champion @3.83ms) + ONE isolated change from the failed R17
// bundle: L1's producer wait is point-to-point (its gate slice gring[.,
// 256j..256j+256) per row is written only by producer block j), so L1 spins
// on pf[j] alone (one line, uniform broadcast read) instead of polling all
// 32 producer flags. Everything else byte-identical to R16 (R17's wave-local
// gated staging REGRESSED 3.83->4.73ms and is fully reverted).
// ---------------------------------------------------------------------------

typedef __attribute__((ext_vector_type(8))) short short8;    // 8 bf16
typedef __attribute__((ext_vector_type(4))) short short4b;   // 4 bf16
typedef __attribute__((ext_vector_type(4))) float f32x4;

#define AS1 __attribute__((address_space(1)))
#define AS3 __attribute__((address_space(3)))

static __device__ __forceinline__ void gload_lds16(const void* g, void* l) {
  __builtin_amdgcn_global_load_lds((const AS1 unsigned int*)g, (AS3 unsigned int*)l,
                                   16, 0, 0);
}

static __device__ __forceinline__ float sigmoidf_(float x) {
  return 1.f / (1.f + __expf(-x));
}

static __device__ __forceinline__ float bf2f(short s) {
  union { unsigned u; float f; } v;
  v.u = ((unsigned)(unsigned short)s) << 16;
  return v.f;
}

static __device__ __forceinline__ unsigned f2bfbits(float f) {
  __hip_bfloat16 h = __float2bfloat16(f);
  union { __hip_bfloat16 h; unsigned short u; } v;
  v.h = h;
  return (unsigned)v.u;
}

// LLC-coherent raw ops
static __device__ __forceinline__ f32x4 ld16_llc(const void* p) {
  f32x4 r;
  asm volatile("global_load_dwordx4 %0, %1, off sc0 sc1" : "=v"(r) : "v"(p) : "memory");
  return r;
}
static __device__ __forceinline__ uint2 ld8_llc(const void* p) {
  uint2 r;
  asm volatile("global_load_dwordx2 %0, %1, off sc0 sc1" : "=v"(r) : "v"(p) : "memory");
  return r;
}
static __device__ __forceinline__ void st16_llc(void* p, f32x4 v) {
  asm volatile("global_store_dwordx4 %0, %1, off sc0 sc1" :: "v"(p), "v"(v) : "memory");
}
static __device__ __forceinline__ void st4_llc(void* p, unsigned v) {
  asm volatile("global_store_dword %0, %1, off sc0 sc1" :: "v"(p), "v"(v) : "memory");
}

// stage 64 KB [32 bat][1024 hid] bf16 -> LDS with XOR swizzle (512 threads).
// Also drains any loads issued before the call (vmcnt(0)).
static __device__ __forceinline__ void stage32(const char* src, char* smem, int tid) {
  f32x4 tmp[8];
#pragma unroll
  for (int i = 0; i < 8; ++i)
    tmp[i] = ld16_llc(src + (size_t)(i * 512 + tid) * 16);
  asm volatile("s_waitcnt vmcnt(0)" ::: "memory");
#pragma unroll
  for (int i = 0; i < 8; ++i) {
    int bo = (i * 512 + tid) * 16;
    int row = bo >> 11;  // local batch row (2048 B each), 0..31
    *(f32x4*)(smem + (bo ^ ((row & 7) << 4))) = tmp[i];
  }
}

// publish completion: data drained to LLC, then ONE plain flag store to this
// block's private (line-padded) flag slot. No RMW -> no arrival serialization.
static __device__ __forceinline__ void arrive_flag(unsigned* slot, unsigned val, int tid) {
  asm volatile("s_waitcnt vmcnt(0)" ::: "memory");  // this wave's stores at LLC
  __syncthreads();                                   // => all waves drained
  if (tid == 0) st4_llc(slot, val);
}

// one-wave poll over 32 line-padded flags: lane i spins on flag (i&31).
// Per-lane divergent exit -> wave proceeds only when ALL flags >= tgt.
static __device__ __forceinline__ void pollf(const unsigned* f, unsigned tgt, int lane) {
  const unsigned* a = f + (lane & 31) * 32;   // 32 words = 128B stride
  while (__hip_atomic_load(a, __ATOMIC_RELAXED, __HIP_MEMORY_SCOPE_AGENT) < tgt) {
  }
}

// --------------------------- f32 -> bf16 convert ---------------------------
__global__ void cvt_bf16(const float* __restrict__ in, __hip_bfloat16* __restrict__ out,
                         int n4) {
  int i = blockIdx.x * 256 + threadIdx.x;
  if (i >= n4) return;
  float4 v = ((const float4*)in)[i];
  out[i * 4 + 0] = __float2bfloat16(v.x);
  out[i * 4 + 1] = __float2bfloat16(v.y);
  out[i * 4 + 2] = __float2bfloat16(v.z);
  out[i * 4 + 3] = __float2bfloat16(v.w);
}

// --------------- f32 -> bf16 with gate-row permutation ---------------------
// out[(hid*4+g)*K + k] = in[(g*1024+hid)*K + k]   (only for the L0 GEMM B)
__global__ void cvt_permrow(const float* __restrict__ in, __hip_bfloat16* __restrict__ out,
                            int K) {
  int k4 = blockIdx.x * 256 + threadIdx.x;
  if (k4 >= (K >> 2)) return;
  int rp = blockIdx.y;
  int src = (rp & 3) * 1024 + (rp >> 2);
  float4 v = ((const float4*)(in + (size_t)src * K))[k4];
  __hip_bfloat16* o = out + (size_t)rp * K + k4 * 4;
  o[0] = __float2bfloat16(v.x);
  o[1] = __float2bfloat16(v.y);
  o[2] = __float2bfloat16(v.z);
  o[3] = __float2bfloat16(v.w);
}

// ------------------ bias sum with gate-row permutation ---------------------
__global__ void bias_perm(const float* __restrict__ b1, const float* __restrict__ b2,
                          float* __restrict__ o) {
  int i = blockIdx.x * 256 + threadIdx.x;  // i = hid*4+g
  if (i >= 4096) return;
  int src = (i & 3) * 1024 + (i >> 2);
  o[i] = b1[src] + b2[src];
}

// ------------------------------ state init --------------------------------
__global__ void init_state(const float* __restrict__ h0, const float* __restrict__ c0,
                           __hip_bfloat16* __restrict__ h_init, float* __restrict__ c_state,
                           int n) {
  int i = blockIdx.x * 256 + threadIdx.x;
  if (i >= n) return;
  h_init[i] = __float2bfloat16(h0[i]);
  c_state[i] = c0[i];
}

// ------------------------------- finalize ---------------------------------
__global__ void finalize_out(const float* __restrict__ hf, const float* __restrict__ cst,
                             float* __restrict__ out_h, float* __restrict__ out_c, int n) {
  int i = blockIdx.x * 256 + threadIdx.x;
  if (i >= n) return;
  out_h[i] = hf[i];
  out_c[i] = cst[i];
}

// --------------------- big GEMM: C = A @ B^T + bias ------------------------
__global__ __launch_bounds__(256) void gemm_bt_bias(
    const __hip_bfloat16* __restrict__ A, const __hip_bfloat16* __restrict__ B,
    __hip_bfloat16* __restrict__ C, const float* __restrict__ bias, int K, int N) {
  const int tid = threadIdx.x;
  const int lane = tid & 63;
  const int wv = tid >> 6;
  const int l15 = lane & 15, l4 = lane >> 4;
  const int bm = blockIdx.x * 128;
  const int bn = blockIdx.y * 128;
  __shared__ alignas(16) __hip_bfloat16 As[128 * 64];
  __shared__ alignas(16) __hip_bfloat16 Bs[128 * 64];
  f32x4 acc[4][4] = {};
  const int wm = (wv >> 1) * 64;
  const int wn = (wv & 1) * 64;

  for (int kt = 0; kt < K; kt += 64) {
    if (kt) __syncthreads();
#pragma unroll
    for (int it = 0; it < 4; ++it) {
      int ci = it * 256 + tid;
      int row = ci >> 3, c8 = ci & 7;
      gload_lds16(A + (bm + row) * K + kt + c8 * 8, As + (it * 256 + wv * 64) * 8);
      gload_lds16(B + (bn + row) * K + kt + c8 * 8, Bs + (it * 256 + wv * 64) * 8);
    }
    __syncthreads();
#pragma unroll
    for (int kk = 0; kk < 64; kk += 32) {
      short8 a[4], b[4];
#pragma unroll
      for (int m = 0; m < 4; ++m)
        a[m] = *(const short8*)(As + (wm + m * 16 + l15) * 64 + kk + l4 * 8);
#pragma unroll
      for (int n = 0; n < 4; ++n)
        b[n] = *(const short8*)(Bs + (wn + n * 16 + l15) * 64 + kk + l4 * 8);
#pragma unroll
      for (int m = 0; m < 4; ++m)
#pragma unroll
        for (int n = 0; n < 4; ++n)
          acc[m][n] = __builtin_amdgcn_mfma_f32_16x16x32_bf16(a[m], b[n], acc[m][n], 0, 0, 0);
    }
  }
#pragma unroll
  for (int n = 0; n < 4; ++n) {
    int col = bn + wn + n * 16 + l15;
    float bs = bias[col];
#pragma unroll
    for (int m = 0; m < 4; ++m) {
#pragma unroll
      for (int j = 0; j < 4; ++j) {
        int row = bm + wm + m * 16 + l4 * 4 + j;
        C[(size_t)row * N + col] = __float2bfloat16(acc[m][n][j] + bs);
      }
    }
  }
}

// ------------- two half-batch three-role persistent pipelines --------------
// LDS: [0,65536) stage; [65536,+8192) xp transpose buffer.
// Flags (per pipeline p, base = ctrs + p*3072 words):
//   l0f@+0, pf@+1024, l1f@+2048; each role = 32 slots x 32-word stride.
// Buffers per pipeline: y0b + p*512*32768, gring + p*1048576, h1r + p*65536.
__global__ __launch_bounds__(512, 1) void lstm_pipeline(
    const __hip_bfloat16* __restrict__ Gin,    // [512][64][4096] L0 preact
    const __hip_bfloat16* __restrict__ Whh0,   // [4096][1024] raw
    const __hip_bfloat16* __restrict__ Whh1,   // [4096][1024] raw
    const __hip_bfloat16* __restrict__ Wih1,   // [4096][1024] raw
    const float* __restrict__ bias1,           // [4096] gate-permuted
    const __hip_bfloat16* __restrict__ hinit,  // [2][64][1024]
    __hip_bfloat16* __restrict__ y0b,          // [2][512][32][1024]
    __hip_bfloat16* __restrict__ gring,        // [2][8][32][4096]
    __hip_bfloat16* __restrict__ h1r,          // [2][2][32][1024]
    float* __restrict__ yout,                  // [512][64][1024] f32 (d_out)
    float* __restrict__ cst,                   // [2][64][1024]
    float* __restrict__ hf,                    // [2][64][1024]
    unsigned* __restrict__ ctrs) {
  extern __shared__ char smem[];
  const int tid = threadIdx.x;
  const int lane = tid & 63;
  const int wv = tid >> 6;                     // 0..7 = hidden row-strip
  const int l15 = lane & 15, l4 = lane >> 4;
  const int bid = blockIdx.x;
  const int pipe = bid >= 96;
  const int wid = pipe ? bid - 96 : bid;       // 0..95 within pipeline
  const int gbat = pipe * 32;                  // pipeline's batch base
  __hip_bfloat16* xp = (__hip_bfloat16*)(smem + 65536);
  unsigned* l0f = ctrs + pipe * 3072;
  unsigned* pf  = l0f + 1024;
  unsigned* l1f = l0f + 2048;
  __hip_bfloat16* y0p = y0b + (size_t)pipe * 512 * 32768;
  __hip_bfloat16* grp_ = gring + (size_t)pipe * 1048576;
  __hip_bfloat16* h1p = h1r + (size_t)pipe * 65536;

  if (wid < 32) {
    // ========================== L0 recurrence ==============================
    const int m = wid;
    const int bbase = m * 32;                  // 32 hidden units
    const int hid = bbase + wv * 4 + l4;
    const int grow = (l15 & 3) * 1024 + bbase + wv * 4 + (l15 >> 2);
    const __hip_bfloat16* wrow = Whh0 + (size_t)grow * 1024 + l4 * 8;
    short8 a[32];
#pragma unroll
    for (int kk = 0; kk < 32; ++kk) a[kk] = *(const short8*)(wrow + kk * 32);
#pragma unroll
    for (int kk = 0; kk < 32; ++kk) asm volatile("" : "+v"(a[kk]));

    float cS[2];
#pragma unroll
    for (int s = 0; s < 2; ++s)
      cS[s] = cst[(gbat + s * 16 + l15) * 1024 + hid];

    short4b gv0 = *(const short4b*)(Gin + (gbat + l15) * 4096 + hid * 4);
    short4b gv1 = *(const short4b*)(Gin + (gbat + 16 + l15) * 4096 + hid * 4);

    for (int t = 0; t < 512; ++t) {
      stage32(t ? (const char*)(y0p + (size_t)(t - 1) * 32768)
                : (const char*)(hinit + (size_t)gbat * 1024),
              smem, tid);
      __syncthreads();

      f32x4 acc[2][4] = {};
#pragma unroll
      for (int kk = 0; kk < 32; ++kk) {
        int ko = kk * 64 + l4 * 16;
#pragma unroll
        for (int s = 0; s < 2; ++s) {
          int bl = s * 16 + l15;               // local batch 0..31
          short8 b = *(const short8*)(smem + ((bl * 2048 + ko) ^ ((bl & 7) << 4)));
          acc[s][kk & 3] =
              __builtin_amdgcn_mfma_f32_16x16x32_bf16(a[kk], b, acc[s][kk & 3], 0, 0, 0);
        }
      }

#pragma unroll
      for (int s = 0; s < 2; ++s) {
        int bl = s * 16 + l15;
        int bat = gbat + bl;
        const short4b gv = s ? gv1 : gv0;
        float gi = acc[s][0][0] + acc[s][1][0] + acc[s][2][0] + acc[s][3][0] + bf2f(gv[0]);
        float gf = acc[s][0][1] + acc[s][1][1] + acc[s][2][1] + acc[s][3][1] + bf2f(gv[1]);
        float gg = acc[s][0][2] + acc[s][1][2] + acc[s][2][2] + acc[s][3][2] + bf2f(gv[2]);
        float go = acc[s][0][3] + acc[s][1][3] + acc[s][2][3] + acc[s][3][3] + bf2f(gv[3]);
        float i_ = sigmoidf_(gi);
        float f_ = sigmoidf_(gf);
        float g_ = tanhf(gg);
        float o_ = sigmoidf_(go);
        cS[s] = f_ * cS[s] + i_ * g_;
        float h = o_ * tanhf(cS[s]);
        xp[bl * 32 + wv * 4 + l4] = __float2bfloat16(h);
        if (t == 511) {
          hf[bat * 1024 + hid] = h;
          cst[bat * 1024 + hid] = cS[s];
        }
      }
      __syncthreads();
      if (tid < 128) {  // 32 bats x 32 hid bf16 = 2KB: 32 rows x 4 x 16B
        int b_ = tid >> 2, part = tid & 3;
        f32x4 v = *(const f32x4*)(xp + b_ * 32 + part * 8);
        st16_llc(y0p + (size_t)t * 32768 + b_ * 1024 + bbase + part * 8, v);
      }
      arrive_flag(l0f + m * 32, (unsigned)(t + 1), tid);
      if (t < 511) {
        gv0 = *(const short4b*)(Gin + (size_t)(t + 1) * 262144 + (gbat + l15) * 4096 + hid * 4);
        gv1 = *(const short4b*)(Gin + (size_t)(t + 1) * 262144 + (gbat + 16 + l15) * 4096 + hid * 4);
        if (tid < 64) pollf(l0f, (unsigned)(t + 1), lane);
        __syncthreads();
      }
    }

  } else if (wid < 64) {
    // ====================== Gin1 producer ==================================
    const int pp = wid - 32;
    const int bbase = pp * 32;
    const int hid = bbase + wv * 4 + l4;
    const int grow = (l15 & 3) * 1024 + bbase + wv * 4 + (l15 >> 2);
    const __hip_bfloat16* wrow = Wih1 + (size_t)grow * 1024 + l4 * 8;  // RAW layout
    short8 a[32];
#pragma unroll
    for (int kk = 0; kk < 32; ++kk) a[kk] = *(const short8*)(wrow + kk * 32);
#pragma unroll
    for (int kk = 0; kk < 32; ++kk) asm volatile("" : "+v"(a[kk]));

    const f32x4 bv = *(const f32x4*)(bias1 + hid * 4);

    for (int t = 0; t < 512; ++t) {
      // wave0: y0[t] ready; wave1: throttle vs L1 (8-slot ring, slack 5)
      if (tid < 64) pollf(l0f, (unsigned)(t + 1), lane);
      else if (tid < 128 && t >= 6) pollf(l1f, (unsigned)(t - 5), lane);
      __syncthreads();

      stage32((const char*)(y0p + (size_t)t * 32768), smem, tid);
      __syncthreads();

      f32x4 acc[2][4] = {};
#pragma unroll
      for (int kk = 0; kk < 32; ++kk) {
        int ko = kk * 64 + l4 * 16;
#pragma unroll
        for (int s = 0; s < 2; ++s) {
          int bl = s * 16 + l15;
          short8 b = *(const short8*)(smem + ((bl * 2048 + ko) ^ ((bl & 7) << 4)));
          acc[s][kk & 3] =
              __builtin_amdgcn_mfma_f32_16x16x32_bf16(a[kk], b, acc[s][kk & 3], 0, 0, 0);
        }
      }

      // xp: [32 bat][128 gate-cols] bf16 (8 KB, 256B/row)
#pragma unroll
      for (int s = 0; s < 2; ++s) {
        int bl = s * 16 + l15;
        float g0 = acc[s][0][0] + acc[s][1][0] + acc[s][2][0] + acc[s][3][0] + bv[0];
        float g1 = acc[s][0][1] + acc[s][1][1] + acc[s][2][1] + acc[s][3][1] + bv[1];
        float g2 = acc[s][0][2] + acc[s][1][2] + acc[s][2][2] + acc[s][3][2] + bv[2];
        float g3 = acc[s][0][3] + acc[s][1][3] + acc[s][2][3] + acc[s][3][3] + bv[3];
        uint2 u;
        u.x = f2bfbits(g0) | (f2bfbits(g1) << 16);
        u.y = f2bfbits(g2) | (f2bfbits(g3) << 16);
        *(uint2*)(xp + bl * 128 + (wv * 4 + l4) * 4) = u;
      }
      __syncthreads();
      {
        // 32 rows x 16 x 16B = 256B/row, all 512 threads
        __hip_bfloat16* gdst = grp_ + (size_t)(t & 7) * 131072;
        int b_ = tid >> 4, part = tid & 15;
        f32x4 v = *(const f32x4*)(xp + b_ * 128 + part * 8);
        st16_llc(gdst + (size_t)b_ * 4096 + bbase * 4 + part * 8, v);
      }
      arrive_flag(pf + pp * 32, (unsigned)(t + 1), tid);
    }

  } else {
    // ========================== L1 recurrence ==============================
    const int j = wid - 64;
    const int bbase = j * 32;
    const int hid = bbase + wv * 4 + l4;
    const int grow = (l15 & 3) * 1024 + bbase + wv * 4 + (l15 >> 2);
    const __hip_bfloat16* wrow = Whh1 + (size_t)grow * 1024 + l4 * 8;
    short8 a[32];
#pragma unroll
    for (int kk = 0; kk < 32; ++kk) a[kk] = *(const short8*)(wrow + kk * 32);
#pragma unroll
    for (int kk = 0; kk < 32; ++kk) asm volatile("" : "+v"(a[kk]));

    float cS[2];
#pragma unroll
    for (int s = 0; s < 2; ++s)
      cS[s] = cst[65536 + (gbat + s * 16 + l15) * 1024 + hid];

    for (int t = 0; t < 512; ++t) {
      // POINT-TO-POINT (R18): this block's gate slice is written only by
      // producer j -> uniform spin on pf[j] (wave0); wave1: h1[t-1] barrier.
      if (tid < 64) {
        while (__hip_atomic_load(pf + j * 32, __ATOMIC_RELAXED,
                                 __HIP_MEMORY_SCOPE_AGENT) < (unsigned)(t + 1)) {
        }
      } else if (tid < 128 && t >= 1) {
        pollf(l1f, (unsigned)t, lane);
      }
      __syncthreads();

      // gate loads issued first; stage32's vmcnt(0) drains both
      const __hip_bfloat16* gsrc = grp_ + (size_t)(t & 7) * 131072;
      uint2 gu[2];
#pragma unroll
      for (int s = 0; s < 2; ++s)
        gu[s] = ld8_llc(gsrc + (size_t)(s * 16 + l15) * 4096 + hid * 4);
      stage32(t ? (const char*)(h1p + (size_t)((t - 1) & 1) * 32768)
                : (const char*)(hinit + 65536 + (size_t)gbat * 1024),
              smem, tid);
      __syncthreads();

      f32x4 acc[2][4] = {};
#pragma unroll
      for (int kk = 0; kk < 32; ++kk) {
        int ko = kk * 64 + l4 * 16;
#pragma unroll
        for (int s = 0; s < 2; ++s) {
          int bl = s * 16 + l15;
          short8 b = *(const short8*)(smem + ((bl * 2048 + ko) ^ ((bl & 7) << 4)));
          acc[s][kk & 3] =
              __builtin_amdgcn_mfma_f32_16x16x32_bf16(a[kk], b, acc[s][kk & 3], 0, 0, 0);
        }
      }

#pragma unroll
      for (int s = 0; s < 2; ++s) {
        int bl = s * 16 + l15;
        int bat = gbat + bl;
        union { uint2 u; short ss[4]; } gp;
        gp.u = gu[s];
        float gi = acc[s][0][0] + acc[s][1][0] + acc[s][2][0] + acc[s][3][0] + bf2f(gp.ss[0]);
        float gf = acc[s][0][1] + acc[s][1][1] + acc[s][2][1] + acc[s][3][1] + bf2f(gp.ss[1]);
        float gg = acc[s][0][2] + acc[s][1][2] + acc[s][2][2] + acc[s][3][2] + bf2f(gp.ss[2]);
        float go = acc[s][0][3] + acc[s][1][3] + acc[s][2][3] + acc[s][3][3] + bf2f(gp.ss[3]);
        float i_ = sigmoidf_(gi);
        float f_ = sigmoidf_(gf);
        float g_ = tanhf(gg);
        float o_ = sigmoidf_(go);
        cS[s] = f_ * cS[s] + i_ * g_;
        float h = o_ * tanhf(cS[s]);
        xp[bl * 32 + wv * 4 + l4] = __float2bfloat16(h);
        if (t == 511) {
          hf[65536 + bat * 1024 + hid] = h;
          cst[65536 + bat * 1024 + hid] = cS[s];
        }
      }
      __syncthreads();
      if (tid < 128) {  // 32 bats x 32 hid bf16: 32 rows x 4 x 16B
        int b_ = tid >> 2, part = tid & 3;
        f32x4 v = *(const f32x4*)(xp + b_ * 32 + part * 8);
        st16_llc(h1p + (size_t)(t & 1) * 32768 + b_ * 1024 + bbase + part * 8, v);
      }
      arrive_flag(l1f + j * 32, (unsigned)(t + 1), tid);

      // yout f32 off the critical path: 32 bats x 32 hid f32 = 32 x 8 x 16B
      if (tid < 256) {
        int b_ = tid >> 3, part = tid & 7;
        short4b hv = *(const short4b*)(xp + b_ * 32 + part * 4);
        f32x4 v;
        v[0] = bf2f(hv[0]); v[1] = bf2f(hv[1]); v[2] = bf2f(hv[2]); v[3] = bf2f(hv[3]);
        *(f32x4*)(yout + (size_t)t * 65536 + (size_t)(gbat + b_) * 1024 + bbase + part * 4) = v;
      }
      // no bottom poll: next step's top-of-loop l1f >= t is the barrier
    }
  }
}

// ---------------------------------------------------------------------------
extern "C" void kernel_launch(void* const* d_in, const int* in_sizes, int n_in,
                              void* d_out_, int out_size, void* d_ws, size_t ws_size,
                              hipStream_t stream) {
  (void)in_sizes; (void)n_in; (void)out_size; (void)ws_size;
  const float* x      = (const float*)d_in[0];
  const float* h0     = (const float*)d_in[1];
  const float* c0     = (const float*)d_in[2];
  const float* w_ih_0 = (const float*)d_in[3];
  const float* w_hh_0 = (const float*)d_in[4];
  const float* b_ih_0 = (const float*)d_in[5];
  const float* b_hh_0 = (const float*)d_in[6];
  const float* w_ih_1 = (const float*)d_in[7];
  const float* w_hh_1 = (const float*)d_in[8];
  const float* b_ih_1 = (const float*)d_in[9];
  const float* b_hh_1 = (const float*)d_in[10];
  float* out = (float*)d_out_;

  char* p = (char*)d_ws;
  auto alloc = [&](size_t bytes) { char* r = p; p += (bytes + 255) & ~(size_t)255; return r; };
  __hip_bfloat16* xb    = (__hip_bfloat16*)alloc(33554432);
  __hip_bfloat16* wbih0 = (__hip_bfloat16*)alloc(4194304);    // permuted rows (GEMM B)
  __hip_bfloat16* wbhh0 = (__hip_bfloat16*)alloc(8388608);    // raw
  __hip_bfloat16* wbih1 = (__hip_bfloat16*)alloc(8388608);    // raw
  __hip_bfloat16* wbhh1 = (__hip_bfloat16*)alloc(8388608);    // raw
  __hip_bfloat16* y0b   = (__hip_bfloat16*)alloc(67108864);   // [2][512][32][1024]
  __hip_bfloat16* Gin   = (__hip_bfloat16*)alloc(268435456);  // L0 preact (full)
  __hip_bfloat16* gring = (__hip_bfloat16*)alloc(4194304);    // [2][8][32][4096]
  __hip_bfloat16* h1r   = (__hip_bfloat16*)alloc(262144);     // [2][2][32][1024]
  __hip_bfloat16* hinit = (__hip_bfloat16*)alloc(262144);     // [2][64][1024]
  float* bsum0          = (float*)alloc(16384);
  float* bsum1          = (float*)alloc(16384);
  float* cst            = (float*)alloc(524288);
  float* hf             = (float*)alloc(524288);
  unsigned* ctrs        = (unsigned*)alloc(32768);            // 2 x 3 x 32 x 128B

  (void)hipFuncSetAttribute((const void*)lstm_pipeline,
                            hipFuncAttributeMaxDynamicSharedMemorySize, 73728);

  cvt_bf16<<<16777216 / 4 / 256, 256, 0, stream>>>(x, xb, 16777216 / 4);
  cvt_permrow<<<dim3(1, 4096), 256, 0, stream>>>(w_ih_0, wbih0, 512);
  cvt_bf16<<<4194304 / 4 / 256, 256, 0, stream>>>(w_hh_0, wbhh0, 4194304 / 4);
  cvt_bf16<<<4194304 / 4 / 256, 256, 0, stream>>>(w_ih_1, wbih1, 4194304 / 4);  // RAW
  cvt_bf16<<<4194304 / 4 / 256, 256, 0, stream>>>(w_hh_1, wbhh1, 4194304 / 4);
  bias_perm<<<16, 256, 0, stream>>>(b_ih_0, b_hh_0, bsum0);
  bias_perm<<<16, 256, 0, stream>>>(b_ih_1, b_hh_1, bsum1);
  init_state<<<131072 / 256, 256, 0, stream>>>(h0, c0, hinit, cst, 131072);
  (void)hipMemsetAsync(ctrs, 0, 32768, stream);

  // L0 preactivations (full batch)
  gemm_bt_bias<<<dim3(256, 32), 256, 0, stream>>>(xb, wbih0, Gin, bsum0, 512, 4096);

  // two half-batch three-role pipelines (one cooperative launch)
  {
    const __hip_bfloat16* g_ = Gin;
    const __hip_bfloat16* w0_ = wbhh0;
    const __hip_bfloat16* w1_ = wbhh1;
    const __hip_bfloat16* wi_ = wbih1;
    const float* b1_ = bsum1;
    const __hip_bfloat16* hi_ = hinit;
    __hip_bfloat16* y0_ = y0b;
    __hip_bfloat16* gr_ = gring;
    __hip_bfloat16* h1_ = h1r;
    float* yo_ = out;
    float* c_ = cst;
    float* hf_ = hf;
    unsigned* ct_ = ctrs;
    void* args[] = {&g_, &w0_, &w1_, &wi_, &b1_, &hi_, &y0_, &gr_, &h1_,
                    &yo_, &c_, &hf_, &ct_};
    (void)hipLaunchCooperativeKernel((void*)lstm_pipeline, dim3(192), dim3(512),
                                     args, 73728, stream);
  }

  finalize_out<<<131072 / 256, 256, 0, stream>>>(hf, cst, out + 33554432, out + 33685504, 131072);
}